// Round 7
// baseline (31.879 us; speedup 1.0000x reference)
//
#include <hip/hip_runtime.h>

// DiscreteLinear: z[b,i] = sum_j weight[a[b],i,j] * x[b,j] + bias[a[b],i]
// B=2048, A=64, D=512.
// R6: R5 structure + 2-way K-split in 8-wave blocks for 2x waves/CU.
//  - waves 0-3: cols 16w..+16, K [0,256); waves 4-7: same cols, K [256,512).
//  - 4096 waves total, LDS 72KB -> 2 blocks/CU -> 16 waves/CU
//    (launch_bounds(512,4) caps VGPR at 128 so occupancy holds).
//  - per-wave K loop fully unrolled: 16 unconditional W loads hoisted ->
//    all in flight during x staging (no conditional array defs -> no
//    scratch, R4 lesson).
//  - K-partials reduced via conflict-free f32 red[4][16][64] overlaid on
//    the dead Xs buffer.

#define NA 64
#define DD 512
#define NB 2048
#define BN 64           // output cols per block
#define NW 8            // waves per block
#define KHALF 256       // K range per wave

typedef __bf16  bf16x8  __attribute__((ext_vector_type(8)));
typedef __bf16  bf16x4  __attribute__((ext_vector_type(4)));
typedef float   floatx4 __attribute__((ext_vector_type(4)));

static __device__ inline bf16x8 cvt8(floatx4 lo, floatx4 hi) {
    bf16x8 r;
    r[0] = (__bf16)lo[0]; r[1] = (__bf16)lo[1];
    r[2] = (__bf16)lo[2]; r[3] = (__bf16)lo[3];
    r[4] = (__bf16)hi[0]; r[5] = (__bf16)hi[1];
    r[6] = (__bf16)hi[2]; r[7] = (__bf16)hi[3];
    return r;
}

__global__ __launch_bounds__(512, 4) void dl_fused(
        const float* __restrict__ x,
        const int*   __restrict__ act,
        const float* __restrict__ weight,
        const float* __restrict__ bias,
        float*       __restrict__ out)
{
    const int a    = blockIdx.x;
    const int tid  = threadIdx.x;
    const int wave = tid >> 6;           // 0..7
    const int lane = tid & 63;
    const int l16  = lane & 15;
    const int kgrp = lane >> 4;
    const int cg   = wave & 3;           // col group 0..3
    const int kh   = wave >> 2;          // K half 0/1
    const int colbase = blockIdx.y * BN;
    const int ncol    = colbase + cg * 16 + l16;

    __shared__ int s_perm[NB];                    // 8 KB
    __shared__ int s_wcnt[NW];
    __shared__ __align__(16) __bf16 Xs[64][DD];   // 64 KB

    // ---- per-block bucket: ballot-compact indices with act[i]==a ----
    const int ibase = wave * (NB / NW);           // 256 samples per wave
    int myact[NB / NW / 64];                      // 4, kept in regs
    int wcnt = 0;
#pragma unroll
    for (int it = 0; it < NB / NW / 64; ++it) {
        myact[it] = act[ibase + it * 64 + lane];
        unsigned long long m = __ballot(myact[it] == a);
        wcnt += (int)__popcll(m);
    }
    if (lane == 0) s_wcnt[wave] = wcnt;
    __syncthreads();
    int cnt = 0, off = 0;
#pragma unroll
    for (int v = 0; v < NW; ++v) {
        const int c = s_wcnt[v];
        if (v < wave) off += c;
        cnt += c;
    }
    if (cnt == 0) return;
#pragma unroll
    for (int it = 0; it < NB / NW / 64; ++it) {
        unsigned long long m = __ballot(myact[it] == a);
        if (myact[it] == a) {
            int pos = off + (int)__popcll(m & ((1ull << lane) - 1ull));
            s_perm[pos] = ibase + it * 64 + lane;
        }
        off += (int)__popcll(m);
    }
    // s_perm made visible by the barrier at the top of the m0 loop.

    const float  bias_v = bias[(size_t)a * DD + ncol];
    const float* wrow   = weight + ((size_t)a * DD + ncol) * DD
                        + kh * KHALF + kgrp * 8;
    const int swzl = (l16 & 7) << 3;     // fragment-read swizzle
    const int srow = tid >> 5;           // 0..15: 16 rows per staging pass
    const int skk  = (tid & 31) << 2;    // 32 lanes x float4 per row

    for (int m0 = 0; m0 < cnt; m0 += 64) {
        __syncthreads();                 // s_perm ready / prior red reads done
        const int rem    = min(cnt - m0, 64);
        const int nchunk = (rem + 15) >> 4;

        // ---- hoist this tile's 16 W loads (unconditional, LDS-independent;
        //      they fly while we stage x below) ----
        floatx4 wreg[16];
#pragma unroll
        for (int kc = 0; kc < 8; ++kc) {
            wreg[2 * kc]     = *(const floatx4*)(wrow + kc * 32);
            wreg[2 * kc + 1] = *(const floatx4*)(wrow + kc * 32 + 4);
        }

        // ---- stage x rows [m0, m0+rem) into swizzled bf16 LDS ----
#pragma unroll
        for (int i = 0; i < 4; ++i) {
            const int r = srow + i * 16;
            if (r < rem) {
                const float* xr = x + (size_t)s_perm[m0 + r] * DD;
                const int rs = (r & 7) << 3;
#pragma unroll
                for (int j = 0; j < 4; ++j) {
                    const int f0 = skk + j * 128;
                    floatx4 v = *(const floatx4*)(xr + f0);
                    bf16x4 bv;
#pragma unroll
                    for (int q = 0; q < 4; ++q) bv[q] = (__bf16)v[q];
                    *(bf16x4*)&Xs[r][f0 ^ rs] = bv;
                }
            }
        }
        __syncthreads();

        // ---- K loop: 8 fully-unrolled K=32 steps over this wave's half ----
        floatx4 acc[4] = {{0,0,0,0},{0,0,0,0},{0,0,0,0},{0,0,0,0}};
#pragma unroll
        for (int kc = 0; kc < 8; ++kc) {
            const bf16x8 bfrag = cvt8(wreg[2 * kc], wreg[2 * kc + 1]);
            const int kb = (kh * KHALF + kc * 32 + kgrp * 8) ^ swzl;
#pragma unroll
            for (int mc = 0; mc < 4; ++mc) {
                if (mc < nchunk) {
                    const bf16x8 afrag = *(const bf16x8*)&Xs[mc * 16 + l16][kb];
                    acc[mc] = __builtin_amdgcn_mfma_f32_16x16x32_bf16(
                                  afrag, bfrag, acc[mc], 0, 0, 0);
                }
            }
        }

        // ---- K-split reduce: overlay red[4][16][64] f32 on the dead Xs ----
        __syncthreads();                 // all Xs reads done
        float* red = (float*)&Xs[0][0];  // 16 KB < 64 KB
        if (kh == 1) {
#pragma unroll
            for (int mc = 0; mc < 4; ++mc)
#pragma unroll
                for (int r = 0; r < 4; ++r)
                    red[(cg * 16 + mc * 4 + r) * 64 + lane] = acc[mc][r];
        }
        __syncthreads();
        if (kh == 0) {
            // Epilogue: C/D layout col = lane&15 (-> ncol), row = kgrp*4+r.
#pragma unroll
            for (int mc = 0; mc < 4; ++mc) {
                if (mc < nchunk) {
#pragma unroll
                    for (int r = 0; r < 4; ++r) {
                        const int mloc = mc * 16 + kgrp * 4 + r;
                        if (mloc < rem) {
                            const float v = acc[mc][r]
                                + red[(cg * 16 + mc * 4 + r) * 64 + lane]
                                + bias_v;
                            out[(size_t)s_perm[m0 + mloc] * DD + ncol] = v;
                        }
                    }
                }
            }
        }
    }
}

extern "C" void kernel_launch(void* const* d_in, const int* in_sizes, int n_in,
                              void* d_out, int out_size, void* d_ws, size_t ws_size,
                              hipStream_t stream) {
    const float* x      = (const float*)d_in[0];
    const int*   act    = (const int*)  d_in[1];
    const float* weight = (const float*)d_in[2];
    const float* bias   = (const float*)d_in[3];
    float*       out    = (float*)d_out;

    dl_fused<<<dim3(NA, DD / BN), 512, 0, stream>>>(x, act, weight, bias, out);
}

// Round 8
// 19.170 us; speedup vs baseline: 1.6629x; 1.6629x over previous
//
#include <hip/hip_runtime.h>

// DiscreteLinear: z[b,i] = sum_j weight[a[b],i,j] * x[b,j] + bias[a[b],i]
// B=2048, A=64, D=512.
// R7: W streamed via global_load_lds DMA ring (the gfx950 MLP mechanism).
// R1/R4/R6 all failed to get memory-level parallelism from VGPR prefetch
// (compiler JIT-serializes at VGPR<=64 or spills to scratch). DMA-to-LDS
// holds outstanding loads in the queue with zero VGPR cost; counted
// vmcnt(4) + raw s_barrier (never __syncthreads = vmcnt(0) drain) keeps
// 2-3 steps (32-48 KB/block) in flight through the whole K loop.
//  - grid (64 actions x 4 col-tiles of 128) = 256 blocks x 512 thr: whole
//    grid resident (1 block/CU, 8 waves).
//  - x staged once per tile into swizzled bf16 LDS (R5-proven); x loads
//    issued BEFORE the DMA issues so their consumption waits vmcnt(6),
//    not vmcnt(0) (in-order counter: never put DMAs older than a load
//    you must consume).
//  - W ring: 4 slots x [128 rows][32 k] fp32 (16 KB/step, 2 calls/step).
//    Swizzle rule #21: linear LDS dest + inverse-swizzled GLOBAL source +
//    swizzled ds_read. LDS[row][u] = G[row][u ^ (row&7)], 16B units.
//  - tail-peeled vmcnt(4)/vmcnt(2)/vmcnt(0) for the last 3 steps.

#define NA 64
#define DD 512
#define NB 2048
#define BN 128          // output cols per block
#define NW 8            // waves per block
#define BK 32           // fp32 k per ring step
#define NSTEPS 16       // DD / BK

typedef __bf16  bf16x8  __attribute__((ext_vector_type(8)));
typedef __bf16  bf16x4  __attribute__((ext_vector_type(4)));
typedef float   floatx4 __attribute__((ext_vector_type(4)));

#define GLD16(g, l)                                                         \
  __builtin_amdgcn_global_load_lds(                                         \
      (const __attribute__((address_space(1))) void*)(g),                   \
      (__attribute__((address_space(3))) void*)(l), 16, 0, 0)
#define VMCNT4   asm volatile("s_waitcnt vmcnt(4)" ::: "memory")
#define VMCNT2   asm volatile("s_waitcnt vmcnt(2)" ::: "memory")
#define VMCNT0   asm volatile("s_waitcnt vmcnt(0)" ::: "memory")
#define LGKMCNT0 asm volatile("s_waitcnt lgkmcnt(0)" ::: "memory")
#define SBAR     __builtin_amdgcn_s_barrier()
#define SCHED0   __builtin_amdgcn_sched_barrier(0)

static __device__ inline bf16x8 cvt8(floatx4 lo, floatx4 hi) {
    bf16x8 r;
    r[0] = (__bf16)lo[0]; r[1] = (__bf16)lo[1];
    r[2] = (__bf16)lo[2]; r[3] = (__bf16)lo[3];
    r[4] = (__bf16)hi[0]; r[5] = (__bf16)hi[1];
    r[6] = (__bf16)hi[2]; r[7] = (__bf16)hi[3];
    return r;
}

__global__ __launch_bounds__(512, 1) void dl_fused(
        const float* __restrict__ x,
        const int*   __restrict__ act,
        const float* __restrict__ weight,
        const float* __restrict__ bias,
        float*       __restrict__ out)
{
    const int a    = blockIdx.x;         // linear id = a + 64*y -> XCD = a%8:
    const int tid  = threadIdx.x;        // all 4 col-tiles of an action share
    const int wave = tid >> 6;           // an XCD -> x stage L2-hits
    const int lane = tid & 63;
    const int l16  = lane & 15;
    const int kgrp = lane >> 4;
    const int colbase = blockIdx.y * BN;
    const int ncol    = colbase + wave * 16 + l16;

    __shared__ int s_perm[NB];                         // 8 KB
    __shared__ int s_wcnt[NW];
    __shared__ __align__(16) __bf16 Xs[64][DD];        // 64 KB
    __shared__ __align__(16) float  Wl[4][BN][BK];     // 64 KB ring

    // ---- fused bucket: ballot-compact indices with act[i]==a ----
    const int ibase = wave * (NB / NW);
    int myact[NB / NW / 64];                           // 4, regs
    int wcnt = 0;
#pragma unroll
    for (int it = 0; it < NB / NW / 64; ++it) {
        myact[it] = act[ibase + it * 64 + lane];
        unsigned long long m = __ballot(myact[it] == a);
        wcnt += (int)__popcll(m);
    }
    if (lane == 0) s_wcnt[wave] = wcnt;
    __syncthreads();
    int cnt = 0, off = 0;
#pragma unroll
    for (int v = 0; v < NW; ++v) {
        const int c = s_wcnt[v];
        if (v < wave) off += c;
        cnt += c;
    }
    if (cnt == 0) return;
#pragma unroll
    for (int it = 0; it < NB / NW / 64; ++it) {
        unsigned long long m = __ballot(myact[it] == a);
        if (myact[it] == a) {
            int pos = off + (int)__popcll(m & ((1ull << lane) - 1ull));
            s_perm[pos] = ibase + it * 64 + lane;
        }
        off += (int)__popcll(m);
    }
    __syncthreads();                      // publish s_perm

    const float  bias_v = bias[(size_t)a * DD + ncol];
    const float* wtile  = weight + (size_t)a * DD * DD + (size_t)colbase * DD;

    // DMA source decomposition (per lane): row-chunk swizzle, 16B units.
    const int r8 = lane >> 3;             // row-within-8 group, 0..7
    const int su = ((lane & 7) ^ r8) << 2;// swizzled float offset in 128B chunk
    const int srow = tid >> 5;            // x staging: 0..15
    const int skk  = (tid & 31) << 2;     // 32 lanes x float4 per row

    for (int m0 = 0; m0 < cnt; m0 += 64) {
        const int rem    = min(cnt - m0, 64);
        const int nchunk = (rem + 15) >> 4;

        // ---- (1) issue x loads (OLDER than DMA: consume waits vmcnt(6)) ----
        floatx4 xv[16];
#pragma unroll
        for (int i = 0; i < 4; ++i) {
            const int r  = srow + 16 * i;
            const int rr = (r < rem) ? r : (rem - 1);   // clamp: unconditional
            const float* xr = x + (size_t)s_perm[m0 + rr] * DD;
#pragma unroll
            for (int j = 0; j < 4; ++j)
                xv[i * 4 + j] = *(const floatx4*)(xr + skk + 128 * j);
        }

        // ---- (2) issue W DMA for steps 0..2 (6 calls in flight) ----
#pragma unroll
        for (int s = 0; s < 3; ++s) {
#pragma unroll
            for (int c = 0; c < 2; ++c)
                GLD16(wtile + (size_t)(c * 64 + wave * 8 + r8) * DD + s * BK + su,
                      (char*)(&Wl[s][0][0]) + c * 8192 + wave * 1024);
        }

        // ---- (3) cvt + swizzled Xs write ----
#pragma unroll
        for (int i = 0; i < 4; ++i) {
            const int r  = srow + 16 * i;
            const int rs = (r & 7) << 3;
#pragma unroll
            for (int j = 0; j < 4; ++j) {
                const int f0 = skk + 128 * j;
                bf16x4 bv;
#pragma unroll
                for (int q = 0; q < 4; ++q) bv[q] = (__bf16)xv[i * 4 + j][q];
                *(bf16x4*)&Xs[r][f0 ^ rs] = bv;
            }
        }
        LGKMCNT0; SBAR; SCHED0;           // Xs + s_perm visible; DMA in flight

        // ---- (4) K loop: 16 steps, 1 barrier + counted vmcnt each ----
        floatx4 acc[4] = {{0,0,0,0},{0,0,0,0},{0,0,0,0},{0,0,0,0}};
        const int h = l16 & 7;
        const int wrow = wave * 16 + l16; // this wave's W rows (= out cols)

        auto compute = [&](int slot, int s) {
            const float* wl = &Wl[slot][0][0];
            const floatx4 blo = *(const floatx4*)(wl + wrow * BK + (((2 * kgrp)     ^ h) << 2));
            const floatx4 bhi = *(const floatx4*)(wl + wrow * BK + (((2 * kgrp + 1) ^ h) << 2));
            const bf16x8 bfrag = cvt8(blo, bhi);
            const int kb = (s * 32 + kgrp * 8) ^ (h << 3);
#pragma unroll
            for (int mc = 0; mc < 4; ++mc) {
                if (mc < nchunk) {
                    const bf16x8 afrag = *(const bf16x8*)&Xs[mc * 16 + l16][kb];
                    acc[mc] = __builtin_amdgcn_mfma_f32_16x16x32_bf16(
                                  afrag, bfrag, acc[mc], 0, 0, 0);
                }
            }
        };

        for (int i = 0; i < NSTEPS - 3; ++i) {
            VMCNT4; SBAR; SCHED0;         // step i landed (everyone), i+1/i+2 fly
            const int s = i + 3;          // prefetch depth 3
            const int slot = s & 3;       // slot (i-1)%4: all waves passed
#pragma unroll                            // compute(i-1) at the barrier above
            for (int c = 0; c < 2; ++c)
                GLD16(wtile + (size_t)(c * 64 + wave * 8 + r8) * DD + s * BK + su,
                      (char*)(&Wl[slot][0][0]) + c * 8192 + wave * 1024);
            compute(i & 3, i);
        }
        VMCNT4; SBAR; SCHED0; compute((NSTEPS - 3) & 3, NSTEPS - 3);
        VMCNT2; SBAR; SCHED0; compute((NSTEPS - 2) & 3, NSTEPS - 2);
        VMCNT0; SBAR; SCHED0; compute((NSTEPS - 1) & 3, NSTEPS - 1);

        // ---- (5) epilogue: C/D layout col = lane&15, row = kgrp*4 + r ----
#pragma unroll
        for (int mc = 0; mc < 4; ++mc) {
            if (mc < nchunk) {
#pragma unroll
                for (int r = 0; r < 4; ++r) {
                    const int mloc = mc * 16 + kgrp * 4 + r;
                    if (mloc < rem)
                        out[(size_t)s_perm[m0 + mloc] * DD + ncol] =
                            acc[mc][r] + bias_v;
                }
            }
        }
        __syncthreads();                  // full drain once per tile; Xs/ring
    }                                     // safe to reuse next tile
}

extern "C" void kernel_launch(void* const* d_in, const int* in_sizes, int n_in,
                              void* d_out, int out_size, void* d_ws, size_t ws_size,
                              hipStream_t stream) {
    const float* x      = (const float*)d_in[0];
    const int*   act    = (const int*)  d_in[1];
    const float* weight = (const float*)d_in[2];
    const float* bias   = (const float*)d_in[3];
    float*       out    = (float*)d_out;

    dl_fused<<<dim3(NA, DD / BN), 512, 0, stream>>>(x, act, weight, bias, out);
}